// Round 2
// baseline (1739.376 us; speedup 1.0000x reference)
//
#include <hip/hip_runtime.h>
#include <hip/hip_bf16.h>

#define N_NODES 100000
#define N_EDGES 1600000
#define HID     64
#define LAYERS  8
#define OUT_DIM 40
#define SCAN_NB 98   // ceil(100000/1024)

// ---------- runtime environment hedges ----------
// flags[0] = 1 if feature inputs are float32 (else bf16)
// flags[1] = 1 if edge_index is int64 (else int32)
__device__ inline float ldext(const void* p, bool f32, size_t i) {
    return f32 ? ((const float*)p)[i]
               : __bfloat162float(((const __hip_bfloat16*)p)[i]);
}
__device__ inline int load_edge(const void* raw, bool is64, long long idx) {
    return is64 ? (int)((const long long*)raw)[idx] : ((const int*)raw)[idx];
}

__global__ void detect_kernel(const void* x, const void* ei, int* flags) {
    int t = threadIdx.x;  // 64 threads
    float v = fabsf(__bfloat162float(((const __hip_bfloat16*)x)[t]));
    bool inband = (v >= 0.00390625f && v <= 16.0f);
    unsigned long long m = __ballot(inband);
    if (t == 0) {
        // bf16 N(0,1) data: ~64/64 in band. fp32 misread as bf16: ~33/64.
        flags[0] = (__popcll(m) < 48) ? 1 : 0;
        const int* e32 = (const int*)ei;
        // int64 little-endian node ids < 2^31 => odd words all zero
        flags[1] = ((e32[1] | e32[3] | e32[5] | e32[7]) == 0) ? 1 : 0;
    }
}

// ---------- setup kernels ----------
__global__ __launch_bounds__(256) void zero_int_kernel(int* p, int n) {
    int i = blockIdx.x * 256 + threadIdx.x;
    if (i < n) p[i] = 0;
}

__global__ __launch_bounds__(256) void count_deg_kernel(const void* ei_raw, const int* __restrict__ flags,
                                                        int* __restrict__ deg) {
    bool is64 = flags[1] != 0;
    int e = blockIdx.x * 256 + threadIdx.x;
    if (e >= N_EDGES) return;
    int d = load_edge(ei_raw, is64, (long long)N_EDGES + e);
    atomicAdd(&deg[d], 1);
}

__global__ __launch_bounds__(256) void calc_dis_kernel(const int* __restrict__ deg, float* __restrict__ dis) {
    int i = blockIdx.x * 256 + threadIdx.x;
    if (i < N_NODES) dis[i] = rsqrtf((float)(deg[i] + 1));  // +1 self-loop
}

// exclusive scan of deg -> row (3-kernel, 1024 elems/block)
__global__ __launch_bounds__(256) void scan1_kernel(const int* __restrict__ deg, int* __restrict__ row,
                                                    int* __restrict__ bsums) {
    __shared__ int sd[256];
    int t = threadIdx.x;
    int base = blockIdx.x * 1024 + t * 4;
    int v[4];
#pragma unroll
    for (int j = 0; j < 4; j++) {
        int idx = base + j;
        v[j] = (idx < N_NODES) ? deg[idx] : 0;
    }
    int s4 = v[0] + v[1] + v[2] + v[3];
    sd[t] = s4;
    __syncthreads();
    for (int off = 1; off < 256; off <<= 1) {
        int x = (t >= off) ? sd[t - off] : 0;
        __syncthreads();
        sd[t] += x;
        __syncthreads();
    }
    int run = sd[t] - s4;  // exclusive
#pragma unroll
    for (int j = 0; j < 4; j++) {
        int idx = base + j;
        if (idx < N_NODES) row[idx] = run;
        run += v[j];
    }
    if (t == 255) bsums[blockIdx.x] = sd[255];
}

__global__ void scan2_kernel(int* bsums) {
    __shared__ int sd[128];
    int t = threadIdx.x;
    int v = (t < SCAN_NB) ? bsums[t] : 0;
    sd[t] = v;
    __syncthreads();
    for (int off = 1; off < 128; off <<= 1) {
        int x = (t >= off) ? sd[t - off] : 0;
        __syncthreads();
        sd[t] += x;
        __syncthreads();
    }
    if (t < SCAN_NB) bsums[t] = sd[t] - v;  // exclusive block offsets
}

__global__ __launch_bounds__(256) void scan3_kernel(int* __restrict__ row, const int* __restrict__ bsums,
                                                    int* __restrict__ cursor) {
    int i = blockIdx.x * 256 + threadIdx.x;
    if (i < N_NODES) {
        int r = row[i] + bsums[i >> 10];
        row[i] = r;
        cursor[i] = r;
    }
    if (i == 0) row[N_NODES] = N_EDGES;
}

__global__ __launch_bounds__(256) void scatter_kernel(const void* ei_raw, const int* __restrict__ flags,
                                                      const float* __restrict__ dis,
                                                      int* __restrict__ cursor, int* __restrict__ csr_src,
                                                      float* __restrict__ csr_norm) {
    bool is64 = flags[1] != 0;
    int e = blockIdx.x * 256 + threadIdx.x;
    if (e >= N_EDGES) return;
    int s = load_edge(ei_raw, is64, e);
    int d = load_edge(ei_raw, is64, (long long)N_EDGES + e);
    int pos = atomicAdd(&cursor[d], 1);
    csr_src[pos] = s;
    csr_norm[pos] = dis[s] * dis[d];
}

// ---------- per-layer matmul: t0[N,64] = h[N,K] @ W[K,64], fp32 acc ----------
// HEXT: h is an external (dtype-flagged) input; else internal bf16 [N,64].
template <int K, bool HEXT>
__global__ __launch_bounds__(256) void mm_kernel(const void* __restrict__ hsrc,
                                                 const void* __restrict__ Wsrc, size_t woff,
                                                 const int* __restrict__ flags,
                                                 __hip_bfloat16* __restrict__ t0) {
    __shared__ float wsh[K * 64];
    __shared__ float hsh[16 * K];
    bool f32 = flags[0] != 0;
    int t = threadIdx.x;
    int nodeBase = blockIdx.x * 16;
    for (int idx = t; idx < K * 64; idx += 256) wsh[idx] = ldext(Wsrc, f32, woff + idx);
    for (int idx = t; idx < 16 * K; idx += 256) {
        int n = idx / K, k = idx & (K - 1);
        size_t gi = (size_t)(nodeBase + n) * K + k;
        hsh[idx] = HEXT ? ldext(hsrc, f32, gi)
                        : __bfloat162float(((const __hip_bfloat16*)hsrc)[gi]);
    }
    __syncthreads();
    int c = t & 63, w = t >> 6;
    float acc0 = 0.f, acc1 = 0.f, acc2 = 0.f, acc3 = 0.f;
#pragma unroll 4
    for (int k = 0; k < K; k++) {
        float wv = wsh[k * 64 + c];
        acc0 += hsh[(w * 4 + 0) * K + k] * wv;
        acc1 += hsh[(w * 4 + 1) * K + k] * wv;
        acc2 += hsh[(w * 4 + 2) * K + k] * wv;
        acc3 += hsh[(w * 4 + 3) * K + k] * wv;
    }
    size_t nb = (size_t)(nodeBase + w * 4) * 64 + c;
    t0[nb]       = __float2bfloat16(acc0);
    t0[nb + 64]  = __float2bfloat16(acc1);
    t0[nb + 128] = __float2bfloat16(acc2);
    t0[nb + 192] = __float2bfloat16(acc3);
}

// ---------- aggregation: one wave per node, lane = feature; h = relu(agg + b) ----------
__global__ __launch_bounds__(256) void agg_kernel(const __hip_bfloat16* __restrict__ t0,
                                                  const int* __restrict__ row_start,
                                                  const int* __restrict__ csr_src,
                                                  const float* __restrict__ csr_norm,
                                                  const float* __restrict__ dis,
                                                  const void* __restrict__ bs, size_t boff,
                                                  const int* __restrict__ flags,
                                                  __hip_bfloat16* __restrict__ h) {
    bool f32 = flags[0] != 0;
    int wave = threadIdx.x >> 6, lane = threadIdx.x & 63;
    int i = blockIdx.x * 4 + wave;
    float di = dis[i];
    float acc = __bfloat162float(t0[(size_t)i * 64 + lane]) * di * di;  // self-loop
    int start = row_start[i], end = row_start[i + 1];
    for (int base = start; base < end; base += 64) {
        int e = base + lane;
        int s = 0;
        float nr = 0.f;
        if (e < end) {
            s = csr_src[e];
            nr = csr_norm[e];
        }
        int cnt = min(64, end - base);
        for (int j = 0; j < cnt; j++) {
            int sj = __shfl(s, j, 64);
            float nj = __shfl(nr, j, 64);
            acc += __bfloat162float(t0[(size_t)sj * 64 + lane]) * nj;
        }
    }
    acc += ldext(bs, f32, boff + lane);
    acc = fmaxf(acc, 0.f);
    h[(size_t)i * 64 + lane] = __float2bfloat16(acc);
}

// ---------- fused JK: out_acc[N,40] += h[N,64] @ lin_w[64l:64l+64, :] ----------
__global__ __launch_bounds__(256) void jkacc_kernel(const __hip_bfloat16* __restrict__ h,
                                                    const void* __restrict__ lin_w, int layer,
                                                    const int* __restrict__ flags,
                                                    float* __restrict__ out_acc) {
    __shared__ float wsh[64 * OUT_DIM];  // 10 KiB
    __shared__ float hsh[32 * 64];       // 8 KiB
    bool f32 = flags[0] != 0;
    int t = threadIdx.x;
    for (int idx = t; idx < 64 * OUT_DIM; idx += 256) {
        int k = idx / OUT_DIM, c = idx - k * OUT_DIM;
        wsh[idx] = ldext(lin_w, f32, (size_t)(layer * 64 + k) * OUT_DIM + c);
    }
    int nodeBase = blockIdx.x * 32;
    for (int idx = t; idx < 32 * 64; idx += 256)
        hsh[idx] = __bfloat162float(h[(size_t)nodeBase * 64 + idx]);
    __syncthreads();
    for (int o = t; o < 32 * OUT_DIM; o += 256) {
        int n = o / OUT_DIM, c = o - n * OUT_DIM;
        float acc = 0.f;
#pragma unroll 8
        for (int k = 0; k < 64; k++) acc += hsh[n * 64 + k] * wsh[k * OUT_DIM + c];
        out_acc[(size_t)(nodeBase + n) * OUT_DIM + c] += acc;
    }
}

// ---------- final: out = out_acc + lin_b, cast per detected dtype ----------
__global__ __launch_bounds__(256) void final_store_kernel(const float* __restrict__ out_acc,
                                                          const void* __restrict__ lin_b,
                                                          const int* __restrict__ flags,
                                                          void* __restrict__ d_out) {
    bool f32 = flags[0] != 0;
    int gid = blockIdx.x * 256 + threadIdx.x;
    if (gid >= N_NODES * OUT_DIM) return;
    int c = gid % OUT_DIM;
    float v = out_acc[gid] + ldext(lin_b, f32, c);
    if (f32) ((float*)d_out)[gid] = v;
    else ((__hip_bfloat16*)d_out)[gid] = __float2bfloat16(v);
}

extern "C" void kernel_launch(void* const* d_in, const int* in_sizes, int n_in,
                              void* d_out, int out_size, void* d_ws, size_t ws_size,
                              hipStream_t stream) {
    const void* x     = d_in[0];
    const void* W0    = d_in[1];
    const void* Ws    = d_in[2];
    const void* bs    = d_in[3];
    const void* lin_w = d_in[4];
    const void* lin_b = d_in[5];
    const void* ei    = d_in[6];

    // workspace carve-up (~56 MB total)
    size_t off = 0;
    auto alloc = [&](size_t bytes) -> void* {
        void* p = (char*)d_ws + off;
        off += (bytes + 511) & ~(size_t)511;
        return p;
    };
    int*   flags    = (int*)alloc(512);
    float* dis      = (float*)alloc((size_t)N_NODES * 4);
    int*   deg      = (int*)alloc((size_t)N_NODES * 4);
    int*   row      = (int*)alloc((size_t)(N_NODES + 1) * 4);
    int*   bsums    = (int*)alloc(128 * 4);
    int*   cursor   = (int*)alloc((size_t)N_NODES * 4);
    int*   csr_src  = (int*)alloc((size_t)N_EDGES * 4);
    float* csr_norm = (float*)alloc((size_t)N_EDGES * 4);
    __hip_bfloat16* t0 = (__hip_bfloat16*)alloc((size_t)N_NODES * HID * 2);
    __hip_bfloat16* h  = (__hip_bfloat16*)alloc((size_t)N_NODES * HID * 2);
    float* out_acc  = (float*)alloc((size_t)N_NODES * OUT_DIM * 4);

    const int nblkN = (N_NODES + 255) / 256;
    const int nblkE = (N_EDGES + 255) / 256;
    const int nblkO = (N_NODES * OUT_DIM) / 256;  // 15625 exact

    detect_kernel<<<1, 64, 0, stream>>>(x, ei, flags);
    zero_int_kernel<<<nblkN, 256, 0, stream>>>(deg, N_NODES);
    zero_int_kernel<<<nblkO, 256, 0, stream>>>((int*)out_acc, N_NODES * OUT_DIM);
    count_deg_kernel<<<nblkE, 256, 0, stream>>>(ei, flags, deg);
    calc_dis_kernel<<<nblkN, 256, 0, stream>>>(deg, dis);
    scan1_kernel<<<SCAN_NB, 256, 0, stream>>>(deg, row, bsums);
    scan2_kernel<<<1, 128, 0, stream>>>(bsums);
    scan3_kernel<<<nblkN, 256, 0, stream>>>(row, bsums, cursor);
    scatter_kernel<<<nblkE, 256, 0, stream>>>(ei, flags, dis, cursor, csr_src, csr_norm);

    for (int l = 0; l < LAYERS; l++) {
        if (l == 0) {
            mm_kernel<128, true><<<N_NODES / 16, 256, 0, stream>>>(x, W0, 0, flags, t0);
        } else {
            mm_kernel<64, false><<<N_NODES / 16, 256, 0, stream>>>(
                h, Ws, (size_t)(l - 1) * HID * HID, flags, t0);
        }
        agg_kernel<<<N_NODES / 4, 256, 0, stream>>>(t0, row, csr_src, csr_norm, dis,
                                                    bs, (size_t)l * HID, flags, h);
        jkacc_kernel<<<N_NODES / 32, 256, 0, stream>>>(h, lin_w, l, flags, out_acc);
    }
    final_store_kernel<<<nblkO, 256, 0, stream>>>(out_acc, lin_b, flags, d_out);
}

// Round 3
// 1261.952 us; speedup vs baseline: 1.3783x; 1.3783x over previous
//
#include <hip/hip_runtime.h>
#include <hip/hip_bf16.h>

#define N_NODES 100000
#define N_EDGES 1600000
#define HID     64
#define LAYERS  8
#define OUT_DIM 40
#define SCAN_NB 98   // ceil(100000/1024)

// ---------- runtime environment hedges ----------
// flags[0] = 1 if feature inputs are float32 (else bf16)
// flags[1] = 1 if edge_index is int64 (else int32)
__device__ inline float ldext(const void* p, bool f32, size_t i) {
    return f32 ? ((const float*)p)[i]
               : __bfloat162float(((const __hip_bfloat16*)p)[i]);
}
__device__ inline int load_edge(const void* raw, bool is64, long long idx) {
    return is64 ? (int)((const long long*)raw)[idx] : ((const int*)raw)[idx];
}
__device__ inline unsigned pack_bf16x2(float lo, float hi) {
    union { __hip_bfloat16 b; unsigned short u; } a, b;
    a.b = __float2bfloat16(lo);
    b.b = __float2bfloat16(hi);
    return ((unsigned)b.u << 16) | a.u;
}

__global__ void detect_kernel(const void* x, const void* ei, int* flags) {
    int t = threadIdx.x;  // 64 threads
    float v = fabsf(__bfloat162float(((const __hip_bfloat16*)x)[t]));
    bool inband = (v >= 0.00390625f && v <= 16.0f);
    unsigned long long m = __ballot(inband);
    if (t == 0) {
        flags[0] = (__popcll(m) < 48) ? 1 : 0;  // fp32 misread as bf16 -> ~33/64 in band
        const int* e32 = (const int*)ei;
        flags[1] = ((e32[1] | e32[3] | e32[5] | e32[7]) == 0) ? 1 : 0;
    }
}

// pack bias (fp32) and lin_w transposed per-layer: lwT[l][c][k] = lin_w[l*64+k][c]
__global__ __launch_bounds__(256) void pack_params_kernel(const void* bs, const void* lin_w,
                                                          const int* __restrict__ flags,
                                                          float* __restrict__ bsf,
                                                          float* __restrict__ lwT) {
    bool f32 = flags[0] != 0;
    int idx = blockIdx.x * 256 + threadIdx.x;
    if (idx < LAYERS * HID) bsf[idx] = ldext(bs, f32, idx);
    if (idx < LAYERS * OUT_DIM * HID) {
        int l = idx / (OUT_DIM * HID);
        int r = idx - l * (OUT_DIM * HID);
        int c = r >> 6, k = r & 63;
        lwT[idx] = ldext(lin_w, f32, (size_t)(l * HID + k) * OUT_DIM + c);
    }
}

// ---------- setup kernels ----------
__global__ __launch_bounds__(256) void zero_int_kernel(int* p, int n) {
    int i = blockIdx.x * 256 + threadIdx.x;
    if (i < n) p[i] = 0;
}

__global__ __launch_bounds__(256) void count_deg_kernel(const void* ei_raw, const int* __restrict__ flags,
                                                        int* __restrict__ deg) {
    bool is64 = flags[1] != 0;
    int e = blockIdx.x * 256 + threadIdx.x;
    if (e >= N_EDGES) return;
    int d = load_edge(ei_raw, is64, (long long)N_EDGES + e);
    atomicAdd(&deg[d], 1);
}

__global__ __launch_bounds__(256) void calc_dis_kernel(const int* __restrict__ deg, float* __restrict__ dis) {
    int i = blockIdx.x * 256 + threadIdx.x;
    if (i < N_NODES) dis[i] = rsqrtf((float)(deg[i] + 1));  // +1 self-loop
}

// exclusive scan of deg -> row (3-kernel, 1024 elems/block)
__global__ __launch_bounds__(256) void scan1_kernel(const int* __restrict__ deg, int* __restrict__ row,
                                                    int* __restrict__ bsums) {
    __shared__ int sd[256];
    int t = threadIdx.x;
    int base = blockIdx.x * 1024 + t * 4;
    int v[4];
#pragma unroll
    for (int j = 0; j < 4; j++) {
        int idx = base + j;
        v[j] = (idx < N_NODES) ? deg[idx] : 0;
    }
    int s4 = v[0] + v[1] + v[2] + v[3];
    sd[t] = s4;
    __syncthreads();
    for (int off = 1; off < 256; off <<= 1) {
        int x = (t >= off) ? sd[t - off] : 0;
        __syncthreads();
        sd[t] += x;
        __syncthreads();
    }
    int run = sd[t] - s4;  // exclusive
#pragma unroll
    for (int j = 0; j < 4; j++) {
        int idx = base + j;
        if (idx < N_NODES) row[idx] = run;
        run += v[j];
    }
    if (t == 255) bsums[blockIdx.x] = sd[255];
}

__global__ void scan2_kernel(int* bsums) {
    __shared__ int sd[128];
    int t = threadIdx.x;
    int v = (t < SCAN_NB) ? bsums[t] : 0;
    sd[t] = v;
    __syncthreads();
    for (int off = 1; off < 128; off <<= 1) {
        int x = (t >= off) ? sd[t - off] : 0;
        __syncthreads();
        sd[t] += x;
        __syncthreads();
    }
    if (t < SCAN_NB) bsums[t] = sd[t] - v;  // exclusive block offsets
}

__global__ __launch_bounds__(256) void scan3_kernel(int* __restrict__ row, const int* __restrict__ bsums,
                                                    int* __restrict__ cursor) {
    int i = blockIdx.x * 256 + threadIdx.x;
    if (i < N_NODES) {
        int r = row[i] + bsums[i >> 10];
        row[i] = r;
        cursor[i] = r;
    }
    if (i == 0) row[N_NODES] = N_EDGES;
}

// single 8B packed store per edge: {norm_bits:32 | src:32} -> 1 cache line touched, not 2
__global__ __launch_bounds__(256) void scatter_kernel(const void* ei_raw, const int* __restrict__ flags,
                                                      const float* __restrict__ dis,
                                                      int* __restrict__ cursor,
                                                      unsigned long long* __restrict__ csr) {
    bool is64 = flags[1] != 0;
    int e = blockIdx.x * 256 + threadIdx.x;
    if (e >= N_EDGES) return;
    int s = load_edge(ei_raw, is64, e);
    int d = load_edge(ei_raw, is64, (long long)N_EDGES + e);
    int pos = atomicAdd(&cursor[d], 1);
    float nr = dis[s] * dis[d];
    csr[pos] = ((unsigned long long)__float_as_uint(nr) << 32) | (unsigned)s;
}

// ---------- per-layer matmul: t0[N,64] = h[N,K] @ W[K,64], fp32 acc ----------
// thread = (node n = t>>4, col-quad c4 = (t&15)*4). per k: 1 b32 (bcast) + 1 b128 + 4 FMA.
template <int K, bool HEXT>
__global__ __launch_bounds__(256) void mm_kernel(const void* __restrict__ hsrc,
                                                 const void* __restrict__ Wsrc, size_t woff,
                                                 const int* __restrict__ flags,
                                                 __hip_bfloat16* __restrict__ t0) {
    constexpr int HS = K + 4;  // pad h rows: kills 4-way bank conflict on broadcast reads
    __shared__ float wsh[K * 64];
    __shared__ float hsh[16 * HS];
    bool f32 = flags[0] != 0;
    int t = threadIdx.x;
    int nodeBase = blockIdx.x * 16;
    for (int idx = t; idx < K * 64; idx += 256) wsh[idx] = ldext(Wsrc, f32, woff + idx);
    for (int idx = t; idx < 16 * K; idx += 256) {
        int n = idx / K, k = idx - n * K;
        size_t gi = (size_t)(nodeBase + n) * K + k;
        hsh[n * HS + k] = HEXT ? ldext(hsrc, f32, gi)
                               : __bfloat162float(((const __hip_bfloat16*)hsrc)[gi]);
    }
    __syncthreads();
    int c4 = (t & 15) * 4, n = t >> 4;
    const float* hrow = hsh + n * HS;
    float a0 = 0.f, a1 = 0.f, a2 = 0.f, a3 = 0.f;
#pragma unroll 8
    for (int k = 0; k < K; k++) {
        float hv = hrow[k];
        float4 wv = *(const float4*)(wsh + k * 64 + c4);
        a0 += hv * wv.x;
        a1 += hv * wv.y;
        a2 += hv * wv.z;
        a3 += hv * wv.w;
    }
    size_t ob = (size_t)(nodeBase + n) * 64 + c4;
    *(uint2*)(t0 + ob) = make_uint2(pack_bf16x2(a0, a1), pack_bf16x2(a2, a3));
}

// ---------- aggregation + bias/relu + fused JK accumulation ----------
// one wave per node. lane = e_sub*8 + f_sub: 8 edges in flight, 8 features (16B) per lane.
__global__ __launch_bounds__(256) void agg_kernel(const __hip_bfloat16* __restrict__ t0,
                                                  const int* __restrict__ row_start,
                                                  const unsigned long long* __restrict__ csr,
                                                  const float* __restrict__ dis,
                                                  const float* __restrict__ bsf,   // this layer, 64 f32
                                                  const float* __restrict__ lwT,   // this layer, [40][64] f32
                                                  __hip_bfloat16* __restrict__ h,
                                                  float* __restrict__ out_acc,
                                                  int first_layer) {
    int wave = threadIdx.x >> 6, lane = threadIdx.x & 63;
    int e_sub = lane >> 3, f_sub = lane & 7;
    int i = blockIdx.x * 4 + wave;
    float acc[8] = {0.f, 0.f, 0.f, 0.f, 0.f, 0.f, 0.f, 0.f};

    if (e_sub == 0) {  // self-loop contribution
        float di = dis[i];
        float di2 = di * di;
        uint4 v = *(const uint4*)(t0 + (size_t)i * 64 + f_sub * 8);
        unsigned u[4] = {v.x, v.y, v.z, v.w};
#pragma unroll
        for (int r = 0; r < 4; r++) {
            acc[2 * r]     += __uint_as_float(u[r] << 16) * di2;
            acc[2 * r + 1] += __uint_as_float(u[r] & 0xffff0000u) * di2;
        }
    }
    int start = row_start[i], end = row_start[i + 1];
    for (int base = start; base + e_sub < end; base += 8) {
        unsigned long long p = csr[base + e_sub];  // same addr for 8 lanes -> broadcast
        int s = (int)(unsigned)(p & 0xffffffffull);
        float nr = __uint_as_float((unsigned)(p >> 32));
        uint4 v = *(const uint4*)(t0 + (size_t)s * 64 + f_sub * 8);
        unsigned u[4] = {v.x, v.y, v.z, v.w};
#pragma unroll
        for (int r = 0; r < 4; r++) {
            acc[2 * r]     += __uint_as_float(u[r] << 16) * nr;
            acc[2 * r + 1] += __uint_as_float(u[r] & 0xffff0000u) * nr;
        }
    }
    // reduce the 8 edge-groups
#pragma unroll
    for (int j = 0; j < 8; j++) {
        acc[j] += __shfl_xor(acc[j], 8);
        acc[j] += __shfl_xor(acc[j], 16);
        acc[j] += __shfl_xor(acc[j], 32);
    }
    // bias + relu (fp32, pre-rounding — closer to the fp32 reference)
#pragma unroll
    for (int j = 0; j < 8; j++) acc[j] = fmaxf(acc[j] + bsf[f_sub * 8 + j], 0.f);
    // store h (bf16) — one copy
    if (e_sub == 0) {
        uint4 pv;
        pv.x = pack_bf16x2(acc[0], acc[1]);
        pv.y = pack_bf16x2(acc[2], acc[3]);
        pv.z = pack_bf16x2(acc[4], acc[5]);
        pv.w = pack_bf16x2(acc[6], acc[7]);
        *(uint4*)(h + (size_t)i * 64 + f_sub * 8) = pv;
    }
    // fused JK: out_acc[i, e_sub*5 .. +5] += h_row @ lwT
    float jkp[5] = {0.f, 0.f, 0.f, 0.f, 0.f};
    const float* wbase = lwT + (size_t)(e_sub * 5) * 64 + f_sub * 8;
#pragma unroll
    for (int cc = 0; cc < 5; cc++) {
        const float* w = wbase + cc * 64;
#pragma unroll
        for (int j = 0; j < 8; j++) jkp[cc] += acc[j] * w[j];
    }
#pragma unroll
    for (int cc = 0; cc < 5; cc++) {
        jkp[cc] += __shfl_xor(jkp[cc], 1);
        jkp[cc] += __shfl_xor(jkp[cc], 2);
        jkp[cc] += __shfl_xor(jkp[cc], 4);
    }
    if (f_sub == 0) {
        float* o = out_acc + (size_t)i * OUT_DIM + e_sub * 5;
        if (first_layer) {
#pragma unroll
            for (int cc = 0; cc < 5; cc++) o[cc] = jkp[cc];
        } else {
#pragma unroll
            for (int cc = 0; cc < 5; cc++) o[cc] += jkp[cc];
        }
    }
}

// ---------- final: out = out_acc + lin_b, cast per detected dtype ----------
__global__ __launch_bounds__(256) void final_store_kernel(const float* __restrict__ out_acc,
                                                          const void* __restrict__ lin_b,
                                                          const int* __restrict__ flags,
                                                          void* __restrict__ d_out) {
    bool f32 = flags[0] != 0;
    int gid = blockIdx.x * 256 + threadIdx.x;
    if (gid >= N_NODES * OUT_DIM) return;
    int c = gid % OUT_DIM;
    float v = out_acc[gid] + ldext(lin_b, f32, c);
    if (f32) ((float*)d_out)[gid] = v;
    else ((__hip_bfloat16*)d_out)[gid] = __float2bfloat16(v);
}

extern "C" void kernel_launch(void* const* d_in, const int* in_sizes, int n_in,
                              void* d_out, int out_size, void* d_ws, size_t ws_size,
                              hipStream_t stream) {
    const void* x     = d_in[0];
    const void* W0    = d_in[1];
    const void* Ws    = d_in[2];
    const void* bs    = d_in[3];
    const void* lin_w = d_in[4];
    const void* lin_b = d_in[5];
    const void* ei    = d_in[6];

    size_t off = 0;
    auto alloc = [&](size_t bytes) -> void* {
        void* p = (char*)d_ws + off;
        off += (bytes + 511) & ~(size_t)511;
        return p;
    };
    int*   flags  = (int*)alloc(512);
    float* dis    = (float*)alloc((size_t)N_NODES * 4);
    int*   deg    = (int*)alloc((size_t)N_NODES * 4);
    int*   row    = (int*)alloc((size_t)(N_NODES + 1) * 4);
    int*   bsums  = (int*)alloc(128 * 4);
    int*   cursor = (int*)alloc((size_t)N_NODES * 4);
    unsigned long long* csr = (unsigned long long*)alloc((size_t)N_EDGES * 8);
    __hip_bfloat16* t0 = (__hip_bfloat16*)alloc((size_t)N_NODES * HID * 2);
    __hip_bfloat16* h  = (__hip_bfloat16*)alloc((size_t)N_NODES * HID * 2);
    float* out_acc = (float*)alloc((size_t)N_NODES * OUT_DIM * 4);
    float* bsf     = (float*)alloc((size_t)LAYERS * HID * 4);
    float* lwT     = (float*)alloc((size_t)LAYERS * OUT_DIM * HID * 4);

    const int nblkN = (N_NODES + 255) / 256;
    const int nblkE = (N_EDGES + 255) / 256;
    const int nblkO = (N_NODES * OUT_DIM) / 256;  // 15625 exact

    detect_kernel<<<1, 64, 0, stream>>>(x, ei, flags);
    pack_params_kernel<<<80, 256, 0, stream>>>(bs, lin_w, flags, bsf, lwT);
    zero_int_kernel<<<nblkN, 256, 0, stream>>>(deg, N_NODES);
    count_deg_kernel<<<nblkE, 256, 0, stream>>>(ei, flags, deg);
    calc_dis_kernel<<<nblkN, 256, 0, stream>>>(deg, dis);
    scan1_kernel<<<SCAN_NB, 256, 0, stream>>>(deg, row, bsums);
    scan2_kernel<<<1, 128, 0, stream>>>(bsums);
    scan3_kernel<<<nblkN, 256, 0, stream>>>(row, bsums, cursor);
    scatter_kernel<<<nblkE, 256, 0, stream>>>(ei, flags, dis, cursor, csr);

    for (int l = 0; l < LAYERS; l++) {
        if (l == 0) {
            mm_kernel<128, true><<<N_NODES / 16, 256, 0, stream>>>(x, W0, 0, flags, t0);
        } else {
            mm_kernel<64, false><<<N_NODES / 16, 256, 0, stream>>>(
                h, Ws, (size_t)(l - 1) * HID * HID, flags, t0);
        }
        agg_kernel<<<N_NODES / 4, 256, 0, stream>>>(t0, row, csr, dis,
                                                    bsf + (size_t)l * HID,
                                                    lwT + (size_t)l * OUT_DIM * HID,
                                                    h, out_acc, l == 0 ? 1 : 0);
    }
    final_store_kernel<<<nblkO, 256, 0, stream>>>(out_acc, lin_b, flags, d_out);
}

// Round 4
// 997.839 us; speedup vs baseline: 1.7431x; 1.2647x over previous
//
#include <hip/hip_runtime.h>
#include <hip/hip_bf16.h>

#define N_NODES 100000
#define N_EDGES 1600000
#define HID     64
#define LAYERS  8
#define OUT_DIM 40
#define SCAN_NB 98   // ceil(100000/1024)

typedef __attribute__((ext_vector_type(8))) short short8;
typedef __attribute__((ext_vector_type(4))) float float4v;

// ---------- runtime environment hedges ----------
// flags[0] = 1 if feature inputs are float32 (else bf16)
// flags[1] = 1 if edge_index is int64 (else int32)
__device__ inline float ldext(const void* p, bool f32, size_t i) {
    return f32 ? ((const float*)p)[i]
               : __bfloat162float(((const __hip_bfloat16*)p)[i]);
}
__device__ inline int load_edge(const void* raw, bool is64, long long idx) {
    return is64 ? (int)((const long long*)raw)[idx] : ((const int*)raw)[idx];
}
__device__ inline unsigned pack_bf16x2(float lo, float hi) {
    union { __hip_bfloat16 b; unsigned short u; } a, b;
    a.b = __float2bfloat16(lo);
    b.b = __float2bfloat16(hi);
    return ((unsigned)b.u << 16) | a.u;
}
__device__ inline unsigned short bf16bits(float v) {
    union { __hip_bfloat16 b; unsigned short u; } a;
    a.b = __float2bfloat16(v);
    return a.u;
}

__global__ void detect_kernel(const void* x, const void* ei, int* flags) {
    int t = threadIdx.x;  // 64 threads
    float v = fabsf(__bfloat162float(((const __hip_bfloat16*)x)[t]));
    bool inband = (v >= 0.00390625f && v <= 16.0f);
    unsigned long long m = __ballot(inband);
    if (t == 0) {
        flags[0] = (__popcll(m) < 48) ? 1 : 0;  // fp32 misread as bf16 -> ~33/64 in band
        const int* e32 = (const int*)ei;
        flags[1] = ((e32[1] | e32[3] | e32[5] | e32[7]) == 0) ? 1 : 0;
    }
}

// pack bias (fp32), lin_w transposed per-layer (lwT[l][c][k]), and W in MFMA
// B-fragment order: wpack[ct][ks][lane][j] = W[ks*32 + (lane>>4)*8 + j][ct*16 + (lane&15)]
__global__ __launch_bounds__(256) void pack_params_kernel(const void* bs, const void* lin_w,
                                                          const void* W0, const void* Ws,
                                                          const int* __restrict__ flags,
                                                          float* __restrict__ bsf,
                                                          float* __restrict__ lwT,
                                                          unsigned short* __restrict__ wpack) {
    bool f32 = flags[0] != 0;
    int gid = blockIdx.x * 256 + threadIdx.x;
    int stride = gridDim.x * 256;
    for (int idx = gid; idx < LAYERS * HID; idx += stride) bsf[idx] = ldext(bs, f32, idx);
    for (int idx = gid; idx < LAYERS * OUT_DIM * HID; idx += stride) {
        int l = idx / (OUT_DIM * HID);
        int r = idx - l * (OUT_DIM * HID);
        int c = r >> 6, k = r & 63;
        lwT[idx] = ldext(lin_w, f32, (size_t)(l * HID + k) * OUT_DIM + c);
    }
    // layer 0: K=128 (KS=4), 8192 elements
    for (int idx = gid; idx < 8192; idx += stride) {
        int j = idx & 7, lane = (idx >> 3) & 63, rest = idx >> 9;
        int ks = rest & 3, ct = rest >> 2;
        int quad = lane >> 4, m = lane & 15;
        wpack[idx] = bf16bits(ldext(W0, f32, (size_t)(ks * 32 + quad * 8 + j) * 64 + ct * 16 + m));
    }
    // layers 1..7: K=64 (KS=2), 4096 elements each
    for (int idx = gid; idx < 7 * 4096; idx += stride) {
        int l = idx >> 12, r = idx & 4095;
        int j = r & 7, lane = (r >> 3) & 63, rest = r >> 9;
        int ks = rest & 1, ct = rest >> 1;
        int quad = lane >> 4, m = lane & 15;
        wpack[8192 + idx] = bf16bits(
            ldext(Ws, f32, (size_t)l * 4096 + (size_t)(ks * 32 + quad * 8 + j) * 64 + ct * 16 + m));
    }
}

// convert x (N x 128) to bf16 if input is fp32; no-op if already bf16
__global__ __launch_bounds__(256) void convert_x_kernel(const void* x, const int* __restrict__ flags,
                                                        __hip_bfloat16* __restrict__ xbf) {
    if (flags[0] == 0) return;
    int i = blockIdx.x * 256 + threadIdx.x;  // 4 floats per thread
    const float4* src = (const float4*)x;
    float4 v = src[i];
    *(uint2*)(xbf + (size_t)i * 4) = make_uint2(pack_bf16x2(v.x, v.y), pack_bf16x2(v.z, v.w));
}

// ---------- setup kernels ----------
__global__ __launch_bounds__(256) void zero_int_kernel(int* p, int n) {
    int i = blockIdx.x * 256 + threadIdx.x;
    if (i < n) p[i] = 0;
}

__global__ __launch_bounds__(256) void count_deg_kernel(const void* ei_raw, const int* __restrict__ flags,
                                                        int* __restrict__ deg) {
    bool is64 = flags[1] != 0;
    int e = blockIdx.x * 256 + threadIdx.x;
    if (e >= N_EDGES) return;
    int d = load_edge(ei_raw, is64, (long long)N_EDGES + e);
    atomicAdd(&deg[d], 1);
}

__global__ __launch_bounds__(256) void calc_dis_kernel(const int* __restrict__ deg, float* __restrict__ dis) {
    int i = blockIdx.x * 256 + threadIdx.x;
    if (i < N_NODES) dis[i] = rsqrtf((float)(deg[i] + 1));  // +1 self-loop
}

// exclusive scan of deg -> row (3-kernel, 1024 elems/block)
__global__ __launch_bounds__(256) void scan1_kernel(const int* __restrict__ deg, int* __restrict__ row,
                                                    int* __restrict__ bsums) {
    __shared__ int sd[256];
    int t = threadIdx.x;
    int base = blockIdx.x * 1024 + t * 4;
    int v[4];
#pragma unroll
    for (int j = 0; j < 4; j++) {
        int idx = base + j;
        v[j] = (idx < N_NODES) ? deg[idx] : 0;
    }
    int s4 = v[0] + v[1] + v[2] + v[3];
    sd[t] = s4;
    __syncthreads();
    for (int off = 1; off < 256; off <<= 1) {
        int x = (t >= off) ? sd[t - off] : 0;
        __syncthreads();
        sd[t] += x;
        __syncthreads();
    }
    int run = sd[t] - s4;  // exclusive
#pragma unroll
    for (int j = 0; j < 4; j++) {
        int idx = base + j;
        if (idx < N_NODES) row[idx] = run;
        run += v[j];
    }
    if (t == 255) bsums[blockIdx.x] = sd[255];
}

__global__ void scan2_kernel(int* bsums) {
    __shared__ int sd[128];
    int t = threadIdx.x;
    int v = (t < SCAN_NB) ? bsums[t] : 0;
    sd[t] = v;
    __syncthreads();
    for (int off = 1; off < 128; off <<= 1) {
        int x = (t >= off) ? sd[t - off] : 0;
        __syncthreads();
        sd[t] += x;
        __syncthreads();
    }
    if (t < SCAN_NB) bsums[t] = sd[t] - v;  // exclusive block offsets
}

__global__ __launch_bounds__(256) void scan3_kernel(int* __restrict__ row, const int* __restrict__ bsums,
                                                    int* __restrict__ cursor) {
    int i = blockIdx.x * 256 + threadIdx.x;
    if (i < N_NODES) {
        int r = row[i] + bsums[i >> 10];
        row[i] = r;
        cursor[i] = r;
    }
    if (i == 0) row[N_NODES] = N_EDGES;
}

// single 8B packed store per edge: {norm_bits:32 | src:32} -> 1 cache line touched, not 2
__global__ __launch_bounds__(256) void scatter_kernel(const void* ei_raw, const int* __restrict__ flags,
                                                      const float* __restrict__ dis,
                                                      int* __restrict__ cursor,
                                                      unsigned long long* __restrict__ csr) {
    bool is64 = flags[1] != 0;
    int e = blockIdx.x * 256 + threadIdx.x;
    if (e >= N_EDGES) return;
    int s = load_edge(ei_raw, is64, e);
    int d = load_edge(ei_raw, is64, (long long)N_EDGES + e);
    int pos = atomicAdd(&cursor[d], 1);
    float nr = dis[s] * dis[d];
    csr[pos] = ((unsigned long long)__float_as_uint(nr) << 32) | (unsigned)s;
}

// ---------- MFMA matmul: t0[N,64] = h[N,K] @ W[K,64], K = KS*32 ----------
// wave = 16-node tile; A straight from global (A[m=lane&15][k=quad*8+j]);
// B pre-packed in fragment order (L2-resident); C/D: col=lane&15, row=quad*4+reg.
template <int KS>
__global__ __launch_bounds__(256) void mm_mfma_kernel(const __hip_bfloat16* __restrict__ h0,
                                                      const __hip_bfloat16* __restrict__ h1,
                                                      const int* __restrict__ flags,
                                                      const unsigned short* __restrict__ wpack,
                                                      __hip_bfloat16* __restrict__ t0) {
    constexpr int K = KS * 32;
    const __hip_bfloat16* hsrc = flags[0] ? h1 : h0;
    int wave = threadIdx.x >> 6, lane = threadIdx.x & 63;
    int quad = lane >> 4, m = lane & 15;
    int nb = blockIdx.x * 64 + wave * 16;
    const short* hrow = (const short*)(hsrc + (size_t)(nb + m) * K) + quad * 8;
    short8 a[KS];
#pragma unroll
    for (int ks = 0; ks < KS; ks++) a[ks] = *(const short8*)(hrow + ks * 32);
    float4v acc[4];
#pragma unroll
    for (int ct = 0; ct < 4; ct++) {
        acc[ct] = (float4v){0.f, 0.f, 0.f, 0.f};
#pragma unroll
        for (int ks = 0; ks < KS; ks++) {
            short8 b = *(const short8*)(wpack + ((ct * KS + ks) * 64 + lane) * 8);
            acc[ct] = __builtin_amdgcn_mfma_f32_16x16x32_bf16(a[ks], b, acc[ct], 0, 0, 0);
        }
    }
#pragma unroll
    for (int ct = 0; ct < 4; ct++) {
#pragma unroll
        for (int r = 0; r < 4; r++) {
            int row = quad * 4 + r;
            t0[(size_t)(nb + row) * 64 + ct * 16 + m] = __float2bfloat16(acc[ct][r]);
        }
    }
}

// ---------- aggregation + bias/relu + fused JK accumulation ----------
// one wave per node. lane = e_sub*8 + f_sub: 8 edges in flight, 8 features (16B) per lane.
__global__ __launch_bounds__(256) void agg_kernel(const __hip_bfloat16* __restrict__ t0,
                                                  const int* __restrict__ row_start,
                                                  const unsigned long long* __restrict__ csr,
                                                  const float* __restrict__ dis,
                                                  const float* __restrict__ bsf,   // this layer, 64 f32
                                                  const float* __restrict__ lwT,   // this layer, [40][64] f32
                                                  __hip_bfloat16* __restrict__ h,
                                                  float* __restrict__ out_acc,
                                                  int first_layer) {
    int wave = threadIdx.x >> 6, lane = threadIdx.x & 63;
    int e_sub = lane >> 3, f_sub = lane & 7;
    int i = blockIdx.x * 4 + wave;
    float acc[8] = {0.f, 0.f, 0.f, 0.f, 0.f, 0.f, 0.f, 0.f};

    if (e_sub == 0) {  // self-loop contribution
        float di = dis[i];
        float di2 = di * di;
        uint4 v = *(const uint4*)(t0 + (size_t)i * 64 + f_sub * 8);
        unsigned u[4] = {v.x, v.y, v.z, v.w};
#pragma unroll
        for (int r = 0; r < 4; r++) {
            acc[2 * r]     += __uint_as_float(u[r] << 16) * di2;
            acc[2 * r + 1] += __uint_as_float(u[r] & 0xffff0000u) * di2;
        }
    }
    int start = row_start[i], end = row_start[i + 1];
    for (int base = start; base + e_sub < end; base += 8) {
        unsigned long long p = csr[base + e_sub];  // same addr for 8 lanes -> broadcast
        int s = (int)(unsigned)(p & 0xffffffffull);
        float nr = __uint_as_float((unsigned)(p >> 32));
        uint4 v = *(const uint4*)(t0 + (size_t)s * 64 + f_sub * 8);
        unsigned u[4] = {v.x, v.y, v.z, v.w};
#pragma unroll
        for (int r = 0; r < 4; r++) {
            acc[2 * r]     += __uint_as_float(u[r] << 16) * nr;
            acc[2 * r + 1] += __uint_as_float(u[r] & 0xffff0000u) * nr;
        }
    }
    // reduce the 8 edge-groups
#pragma unroll
    for (int j = 0; j < 8; j++) {
        acc[j] += __shfl_xor(acc[j], 8);
        acc[j] += __shfl_xor(acc[j], 16);
        acc[j] += __shfl_xor(acc[j], 32);
    }
    // bias + relu (fp32, pre-rounding)
#pragma unroll
    for (int j = 0; j < 8; j++) acc[j] = fmaxf(acc[j] + bsf[f_sub * 8 + j], 0.f);
    // store h (bf16) — one copy
    if (e_sub == 0) {
        uint4 pv;
        pv.x = pack_bf16x2(acc[0], acc[1]);
        pv.y = pack_bf16x2(acc[2], acc[3]);
        pv.z = pack_bf16x2(acc[4], acc[5]);
        pv.w = pack_bf16x2(acc[6], acc[7]);
        *(uint4*)(h + (size_t)i * 64 + f_sub * 8) = pv;
    }
    // fused JK: out_acc[i, e_sub*5 .. +5] += h_row @ lwT
    float jkp[5] = {0.f, 0.f, 0.f, 0.f, 0.f};
    const float* wbase = lwT + (size_t)(e_sub * 5) * 64 + f_sub * 8;
#pragma unroll
    for (int cc = 0; cc < 5; cc++) {
        const float* w = wbase + cc * 64;
#pragma unroll
        for (int j = 0; j < 8; j++) jkp[cc] += acc[j] * w[j];
    }
#pragma unroll
    for (int cc = 0; cc < 5; cc++) {
        jkp[cc] += __shfl_xor(jkp[cc], 1);
        jkp[cc] += __shfl_xor(jkp[cc], 2);
        jkp[cc] += __shfl_xor(jkp[cc], 4);
    }
    if (f_sub == 0) {
        float* o = out_acc + (size_t)i * OUT_DIM + e_sub * 5;
        if (first_layer) {
#pragma unroll
            for (int cc = 0; cc < 5; cc++) o[cc] = jkp[cc];
        } else {
#pragma unroll
            for (int cc = 0; cc < 5; cc++) o[cc] += jkp[cc];
        }
    }
}

// ---------- final: out = out_acc + lin_b, cast per detected dtype ----------
__global__ __launch_bounds__(256) void final_store_kernel(const float* __restrict__ out_acc,
                                                          const void* __restrict__ lin_b,
                                                          const int* __restrict__ flags,
                                                          void* __restrict__ d_out) {
    bool f32 = flags[0] != 0;
    int gid = blockIdx.x * 256 + threadIdx.x;
    if (gid >= N_NODES * OUT_DIM) return;
    int c = gid % OUT_DIM;
    float v = out_acc[gid] + ldext(lin_b, f32, c);
    if (f32) ((float*)d_out)[gid] = v;
    else ((__hip_bfloat16*)d_out)[gid] = __float2bfloat16(v);
}

extern "C" void kernel_launch(void* const* d_in, const int* in_sizes, int n_in,
                              void* d_out, int out_size, void* d_ws, size_t ws_size,
                              hipStream_t stream) {
    const void* x     = d_in[0];
    const void* W0    = d_in[1];
    const void* Ws    = d_in[2];
    const void* bs    = d_in[3];
    const void* lin_w = d_in[4];
    const void* lin_b = d_in[5];
    const void* ei    = d_in[6];

    size_t off = 0;
    auto alloc = [&](size_t bytes) -> void* {
        void* p = (char*)d_ws + off;
        off += (bytes + 511) & ~(size_t)511;
        return p;
    };
    int*   flags  = (int*)alloc(512);
    float* dis    = (float*)alloc((size_t)N_NODES * 4);
    int*   deg    = (int*)alloc((size_t)N_NODES * 4);
    int*   row    = (int*)alloc((size_t)(N_NODES + 1) * 4);
    int*   bsums  = (int*)alloc(128 * 4);
    int*   cursor = (int*)alloc((size_t)N_NODES * 4);
    unsigned long long* csr = (unsigned long long*)alloc((size_t)N_EDGES * 8);
    // +32 rows padding: mm grid (1563*64=100032) overshoots N by 32 rows
    __hip_bfloat16* t0  = (__hip_bfloat16*)alloc((size_t)(N_NODES + 32) * HID * 2);
    __hip_bfloat16* h   = (__hip_bfloat16*)alloc((size_t)(N_NODES + 32) * HID * 2);
    __hip_bfloat16* xbf = (__hip_bfloat16*)alloc((size_t)(N_NODES + 32) * 128 * 2);
    float* out_acc = (float*)alloc((size_t)N_NODES * OUT_DIM * 4);
    float* bsf     = (float*)alloc((size_t)LAYERS * HID * 4);
    float* lwT     = (float*)alloc((size_t)LAYERS * OUT_DIM * HID * 4);
    unsigned short* wpack = (unsigned short*)alloc(36864 * 2);

    const int nblkN = (N_NODES + 255) / 256;
    const int nblkE = (N_EDGES + 255) / 256;
    const int nblkO = (N_NODES * OUT_DIM) / 256;   // 15625 exact
    const int nblkMM = (N_NODES + 63) / 64;        // 1563

    detect_kernel<<<1, 64, 0, stream>>>(x, ei, flags);
    pack_params_kernel<<<80, 256, 0, stream>>>(bs, lin_w, W0, Ws, flags, bsf, lwT, wpack);
    convert_x_kernel<<<(N_NODES * 128 / 4) / 256, 256, 0, stream>>>(x, flags, xbf);
    zero_int_kernel<<<nblkN, 256, 0, stream>>>(deg, N_NODES);
    count_deg_kernel<<<nblkE, 256, 0, stream>>>(ei, flags, deg);
    calc_dis_kernel<<<nblkN, 256, 0, stream>>>(deg, dis);
    scan1_kernel<<<SCAN_NB, 256, 0, stream>>>(deg, row, bsums);
    scan2_kernel<<<1, 128, 0, stream>>>(bsums);
    scan3_kernel<<<nblkN, 256, 0, stream>>>(row, bsums, cursor);
    scatter_kernel<<<nblkE, 256, 0, stream>>>(ei, flags, dis, cursor, csr);

    for (int l = 0; l < LAYERS; l++) {
        if (l == 0) {
            mm_mfma_kernel<4><<<nblkMM, 256, 0, stream>>>(
                (const __hip_bfloat16*)x, xbf, flags, wpack, t0);
        } else {
            mm_mfma_kernel<2><<<nblkMM, 256, 0, stream>>>(
                h, h, flags, wpack + 8192 + (size_t)(l - 1) * 4096, t0);
        }
        agg_kernel<<<N_NODES / 4, 256, 0, stream>>>(t0, row, csr, dis,
                                                    bsf + (size_t)l * HID,
                                                    lwT + (size_t)l * OUT_DIM * HID,
                                                    h, out_acc, l == 0 ? 1 : 0);
    }
    final_store_kernel<<<nblkO, 256, 0, stream>>>(out_acc, lin_b, flags, d_out);
}